// Round 1
// baseline (1120.194 us; speedup 1.0000x reference)
//
#include <hip/hip_runtime.h>

#define N_NODES 50000
#define F_IN    512
#define F_OUT   96
#define N_EDGES 800000

// ---------------------------------------------------------------------------
// GEMM: support[N_NODES][96] = x[N_NODES][512] @ w[512][96]   (all f32)
// Tile: 64 rows x 96 cols per block, K staged in 32-wide panels in LDS.
// 256 threads, each computes a 4x6 sub-tile (acc[4][6]).
// ---------------------------------------------------------------------------
__global__ __launch_bounds__(256) void gcn_gemm(const float* __restrict__ x,
                                                const float* __restrict__ w,
                                                float* __restrict__ support) {
    __shared__ float sX[64][33];   // +1 pad to break bank conflicts
    __shared__ float sW[32][96];

    const int tid = threadIdx.x;
    const int tx  = tid & 15;   // col group: cols tx*6 .. tx*6+5
    const int ty  = tid >> 4;   // row group: rows ty*4 .. ty*4+3
    const int r0  = blockIdx.x * 64;

    float acc[4][6];
    #pragma unroll
    for (int i = 0; i < 4; ++i)
        #pragma unroll
        for (int j = 0; j < 6; ++j) acc[i][j] = 0.0f;

    const int lrow = tid >> 2;  // 0..63 : row this thread loads
    const int lf4  = tid & 3;   // 0..3  : which float4 (plus +4 on 2nd pass)

    for (int k0 = 0; k0 < F_IN; k0 += 32) {
        // --- load X tile (64 x 32) as float4s ---
        #pragma unroll
        for (int p = 0; p < 2; ++p) {
            const int f4 = lf4 + p * 4;          // 0..7
            const int gr = r0 + lrow;
            float4 v = make_float4(0.f, 0.f, 0.f, 0.f);
            if (gr < N_NODES)
                v = *reinterpret_cast<const float4*>(x + (size_t)gr * F_IN + k0 + f4 * 4);
            sX[lrow][f4 * 4 + 0] = v.x;
            sX[lrow][f4 * 4 + 1] = v.y;
            sX[lrow][f4 * 4 + 2] = v.z;
            sX[lrow][f4 * 4 + 3] = v.w;
        }
        // --- load W tile (32 x 96) ---
        #pragma unroll
        for (int p = 0; p < 12; ++p) {
            const int idx = p * 256 + tid;       // 0..3071
            const int kk  = idx / 96;
            const int c   = idx - kk * 96;
            sW[kk][c] = w[(size_t)(k0 + kk) * F_OUT + c];
        }
        __syncthreads();

        // --- outer-product accumulate over the K panel ---
        #pragma unroll
        for (int kk = 0; kk < 32; ++kk) {
            float xr[4], wr[6];
            #pragma unroll
            for (int i = 0; i < 4; ++i) xr[i] = sX[ty * 4 + i][kk];
            #pragma unroll
            for (int j = 0; j < 6; ++j) wr[j] = sW[kk][tx * 6 + j];
            #pragma unroll
            for (int i = 0; i < 4; ++i)
                #pragma unroll
                for (int j = 0; j < 6; ++j)
                    acc[i][j] = fmaf(xr[i], wr[j], acc[i][j]);
        }
        __syncthreads();
    }

    // --- write support tile ---
    #pragma unroll
    for (int i = 0; i < 4; ++i) {
        const int gr = r0 + ty * 4 + i;
        if (gr < N_NODES) {
            float* o = support + (size_t)gr * F_OUT + tx * 6;
            #pragma unroll
            for (int j = 0; j < 6; ++j) o[j] = acc[i][j];
        }
    }
}

// ---------------------------------------------------------------------------
// Scatter: for each edge e, out[row[e]] += val[e] * support[col[e]]
// One thread per (edge, float4-of-features): 800000 * 24 threads.
// ---------------------------------------------------------------------------
__global__ __launch_bounds__(256) void gcn_scatter(const int* __restrict__ erow,
                                                   const int* __restrict__ ecol,
                                                   const float* __restrict__ eval,
                                                   const float* __restrict__ support,
                                                   float* __restrict__ out) {
    const long long i = (long long)blockIdx.x * blockDim.x + threadIdx.x;
    const long long total = (long long)N_EDGES * 24;
    if (i >= total) return;
    const int e  = (int)(i / 24);
    const int f4 = (int)(i - (long long)e * 24);

    const int   r = erow[e];
    const int   c = ecol[e];
    const float v = eval[e];

    const float4 s = *reinterpret_cast<const float4*>(support + (size_t)c * F_OUT + f4 * 4);
    float* o = out + (size_t)r * F_OUT + f4 * 4;
    atomicAdd(o + 0, v * s.x);
    atomicAdd(o + 1, v * s.y);
    atomicAdd(o + 2, v * s.z);
    atomicAdd(o + 3, v * s.w);
}

// ---------------------------------------------------------------------------
// In-place ReLU on out (float4 granularity; N_NODES*96 divisible by 4)
// ---------------------------------------------------------------------------
__global__ __launch_bounds__(256) void gcn_relu(float* __restrict__ out) {
    const int i = blockIdx.x * blockDim.x + threadIdx.x;
    const int total4 = N_NODES * F_OUT / 4;   // 1.2M
    if (i >= total4) return;
    float4 v = reinterpret_cast<float4*>(out)[i];
    v.x = fmaxf(v.x, 0.f);
    v.y = fmaxf(v.y, 0.f);
    v.z = fmaxf(v.z, 0.f);
    v.w = fmaxf(v.w, 0.f);
    reinterpret_cast<float4*>(out)[i] = v;
}

extern "C" void kernel_launch(void* const* d_in, const int* in_sizes, int n_in,
                              void* d_out, int out_size, void* d_ws, size_t ws_size,
                              hipStream_t stream) {
    const float* x    = (const float*)d_in[0];
    const int*   erow = (const int*)d_in[1];
    const int*   ecol = (const int*)d_in[2];
    const float* eval = (const float*)d_in[3];
    const float* w    = (const float*)d_in[4];
    float*       out  = (float*)d_out;
    float*       support = (float*)d_ws;   // 50000*96*4 = 19.2 MB scratch

    // out accumulates via atomics -> must start at zero every call
    hipMemsetAsync(d_out, 0, (size_t)N_NODES * F_OUT * sizeof(float), stream);

    // support = x @ w
    gcn_gemm<<<(N_NODES + 63) / 64, 256, 0, stream>>>(x, w, support);

    // out += scatter(edges)
    const long long total = (long long)N_EDGES * 24;
    const int sblocks = (int)((total + 255) / 256);
    gcn_scatter<<<sblocks, 256, 0, stream>>>(erow, ecol, eval, support, out);

    // out = relu(out)
    const int rblocks = (N_NODES * F_OUT / 4 + 255) / 256;
    gcn_relu<<<rblocks, 256, 0, stream>>>(out);
}

// Round 2
// 254.324 us; speedup vs baseline: 4.4046x; 4.4046x over previous
//
#include <hip/hip_runtime.h>

#define N_NODES 50000
#define F_IN    512
#define F_OUT   96
#define N_EDGES 800000
#define SCAN_BLOCKS ((N_NODES + 255) / 256)   // 196

// ---------------------------------------------------------------------------
// GEMM: support[N_NODES][96] = x[N_NODES][512] @ w[512][96]   (all f32)
// (unchanged from R1 — not the bottleneck this round)
// ---------------------------------------------------------------------------
__global__ __launch_bounds__(256) void gcn_gemm(const float* __restrict__ x,
                                                const float* __restrict__ w,
                                                float* __restrict__ support) {
    __shared__ float sX[64][33];
    __shared__ float sW[32][96];

    const int tid = threadIdx.x;
    const int tx  = tid & 15;
    const int ty  = tid >> 4;
    const int r0  = blockIdx.x * 64;

    float acc[4][6];
    #pragma unroll
    for (int i = 0; i < 4; ++i)
        #pragma unroll
        for (int j = 0; j < 6; ++j) acc[i][j] = 0.0f;

    const int lrow = tid >> 2;
    const int lf4  = tid & 3;

    for (int k0 = 0; k0 < F_IN; k0 += 32) {
        #pragma unroll
        for (int p = 0; p < 2; ++p) {
            const int f4 = lf4 + p * 4;
            const int gr = r0 + lrow;
            float4 v = make_float4(0.f, 0.f, 0.f, 0.f);
            if (gr < N_NODES)
                v = *reinterpret_cast<const float4*>(x + (size_t)gr * F_IN + k0 + f4 * 4);
            sX[lrow][f4 * 4 + 0] = v.x;
            sX[lrow][f4 * 4 + 1] = v.y;
            sX[lrow][f4 * 4 + 2] = v.z;
            sX[lrow][f4 * 4 + 3] = v.w;
        }
        #pragma unroll
        for (int p = 0; p < 12; ++p) {
            const int idx = p * 256 + tid;
            const int kk  = idx / 96;
            const int c   = idx - kk * 96;
            sW[kk][c] = w[(size_t)(k0 + kk) * F_OUT + c];
        }
        __syncthreads();

        #pragma unroll
        for (int kk = 0; kk < 32; ++kk) {
            float xr[4], wr[6];
            #pragma unroll
            for (int i = 0; i < 4; ++i) xr[i] = sX[ty * 4 + i][kk];
            #pragma unroll
            for (int j = 0; j < 6; ++j) wr[j] = sW[kk][tx * 6 + j];
            #pragma unroll
            for (int i = 0; i < 4; ++i)
                #pragma unroll
                for (int j = 0; j < 6; ++j)
                    acc[i][j] = fmaf(xr[i], wr[j], acc[i][j]);
        }
        __syncthreads();
    }

    #pragma unroll
    for (int i = 0; i < 4; ++i) {
        const int gr = r0 + ty * 4 + i;
        if (gr < N_NODES) {
            float* o = support + (size_t)gr * F_OUT + tx * 6;
            #pragma unroll
            for (int j = 0; j < 6; ++j) o[j] = acc[i][j];
        }
    }
}

// ---------------------------------------------------------------------------
// CSR build: histogram -> exclusive scan (3 small kernels) -> bucket fill
// ---------------------------------------------------------------------------
__global__ __launch_bounds__(256) void k_hist(const int* __restrict__ erow,
                                              int* __restrict__ counts) {
    const int e = blockIdx.x * 256 + threadIdx.x;
    if (e < N_EDGES) atomicAdd(&counts[erow[e]], 1);
}

__global__ __launch_bounds__(256) void k_scan_block(const int* __restrict__ counts,
                                                    int* __restrict__ offsets,
                                                    int* __restrict__ partials) {
    __shared__ int s[256];
    const int t = threadIdx.x;
    const int i = blockIdx.x * 256 + t;
    const int v = (i < N_NODES) ? counts[i] : 0;
    s[t] = v;
    __syncthreads();
    #pragma unroll
    for (int off = 1; off < 256; off <<= 1) {
        const int a = (t >= off) ? s[t - off] : 0;
        __syncthreads();
        s[t] += a;
        __syncthreads();
    }
    if (i < N_NODES) offsets[i] = s[t] - v;          // exclusive, chunk-local
    if (t == 255) partials[blockIdx.x] = s[255];      // chunk total
}

__global__ __launch_bounds__(256) void k_scan_partials(int* __restrict__ partials) {
    __shared__ int s[256];
    const int t = threadIdx.x;
    const int v = (t < SCAN_BLOCKS) ? partials[t] : 0;
    s[t] = v;
    __syncthreads();
    #pragma unroll
    for (int off = 1; off < 256; off <<= 1) {
        const int a = (t >= off) ? s[t - off] : 0;
        __syncthreads();
        s[t] += a;
        __syncthreads();
    }
    if (t < SCAN_BLOCKS) partials[t] = s[t] - v;      // exclusive
}

__global__ __launch_bounds__(256) void k_scan_add(int* __restrict__ offsets,
                                                  const int* __restrict__ partials) {
    const int i = blockIdx.x * 256 + threadIdx.x;
    if (i < N_NODES) offsets[i] += partials[blockIdx.x];
    if (i == 0) offsets[N_NODES] = N_EDGES;
}

__global__ __launch_bounds__(256) void k_fill(const int* __restrict__ erow,
                                              const int* __restrict__ ecol,
                                              const float* __restrict__ eval,
                                              const int* __restrict__ offsets,
                                              int* __restrict__ cursor,
                                              float2* __restrict__ bucket) {
    const int e = blockIdx.x * 256 + threadIdx.x;
    if (e < N_EDGES) {
        const int r = erow[e];
        const int pos = offsets[r] + atomicAdd(&cursor[r], 1);
        bucket[pos] = make_float2(__int_as_float(ecol[e]), eval[e]);
    }
}

// ---------------------------------------------------------------------------
// Gather: thread = (row, f4), f4 in [0,24). Accumulate row's edges in
// registers, fuse ReLU, write out exactly once. No atomics.
// ---------------------------------------------------------------------------
__global__ __launch_bounds__(256) void k_gather(const int* __restrict__ offsets,
                                                const float2* __restrict__ bucket,
                                                const float* __restrict__ support,
                                                float* __restrict__ out) {
    const int gid = blockIdx.x * 256 + threadIdx.x;
    if (gid >= N_NODES * 24) return;
    const int r  = gid / 24;
    const int f4 = gid - r * 24;

    const int beg = offsets[r];
    const int end = offsets[r + 1];

    float4 acc = make_float4(0.f, 0.f, 0.f, 0.f);
    for (int i = beg; i < end; ++i) {
        const float2 cv = bucket[i];               // broadcast across row's lanes
        const int   c = __float_as_int(cv.x);
        const float v = cv.y;
        const float4 s = *reinterpret_cast<const float4*>(
            support + (size_t)c * F_OUT + f4 * 4);
        acc.x = fmaf(v, s.x, acc.x);
        acc.y = fmaf(v, s.y, acc.y);
        acc.z = fmaf(v, s.z, acc.z);
        acc.w = fmaf(v, s.w, acc.w);
    }

    acc.x = fmaxf(acc.x, 0.f);
    acc.y = fmaxf(acc.y, 0.f);
    acc.z = fmaxf(acc.z, 0.f);
    acc.w = fmaxf(acc.w, 0.f);
    *reinterpret_cast<float4*>(out + (size_t)r * F_OUT + f4 * 4) = acc;
}

extern "C" void kernel_launch(void* const* d_in, const int* in_sizes, int n_in,
                              void* d_out, int out_size, void* d_ws, size_t ws_size,
                              hipStream_t stream) {
    const float* x    = (const float*)d_in[0];
    const int*   erow = (const int*)d_in[1];
    const int*   ecol = (const int*)d_in[2];
    const float* eval = (const float*)d_in[3];
    const float* w    = (const float*)d_in[4];
    float*       out  = (float*)d_out;

    // workspace layout
    float*  support  = (float*)d_ws;                       // 4.8M floats (19.2 MB)
    int*    counts   = (int*)(support + 4800000);          // 50000
    int*    cursor   = counts + N_NODES;                   // 50000
    int*    offsets  = cursor + N_NODES;                   // 50001 (padded to 50064)
    int*    partials = offsets + 50064;                    // 256
    float2* bucket   = (float2*)(partials + 256);          // 800000 float2 (6.4 MB)

    // zero counts + cursor (contiguous) every call
    hipMemsetAsync(counts, 0, 2 * N_NODES * sizeof(int), stream);

    // support = x @ w
    gcn_gemm<<<(N_NODES + 63) / 64, 256, 0, stream>>>(x, w, support);

    // CSR build
    const int eblocks = (N_EDGES + 255) / 256;             // 3125
    k_hist<<<eblocks, 256, 0, stream>>>(erow, counts);
    k_scan_block<<<SCAN_BLOCKS, 256, 0, stream>>>(counts, offsets, partials);
    k_scan_partials<<<1, 256, 0, stream>>>(partials);
    k_scan_add<<<SCAN_BLOCKS, 256, 0, stream>>>(offsets, partials);
    k_fill<<<eblocks, 256, 0, stream>>>(erow, ecol, eval, offsets, cursor, bucket);

    // out = relu(A @ support)
    const int gthreads = N_NODES * 24;                     // 1.2M
    k_gather<<<(gthreads + 255) / 256, 256, 0, stream>>>(offsets, bucket, support, out);
}

// Round 3
// 214.707 us; speedup vs baseline: 5.2173x; 1.1845x over previous
//
#include <hip/hip_runtime.h>

#define N_NODES 50000
#define F_IN    512
#define F_OUT   96
#define N_EDGES 800000
#define SCAN_BLOCKS ((N_NODES + 255) / 256)   // 196

typedef __attribute__((ext_vector_type(8))) short bf16x8;
typedef __attribute__((ext_vector_type(4))) float f32x4;

// f32 -> bf16 round-to-nearest-even (bit pattern)
__device__ __forceinline__ unsigned short f2bf(float f) {
    unsigned int u = __float_as_uint(f);
    unsigned int r = (u + 0x7FFFu + ((u >> 16) & 1u)) >> 16;
    return (unsigned short)r;
}

// ---------------------------------------------------------------------------
// Cast + transpose weight: w[512][96] f32  ->  wT[96][512] bf16
// ---------------------------------------------------------------------------
__global__ __launch_bounds__(256) void k_wcast(const float* __restrict__ w,
                                               unsigned short* __restrict__ wT) {
    const int i = blockIdx.x * 256 + threadIdx.x;   // 0..49151
    if (i < F_OUT * F_IN) {
        const int n = i >> 9;        // / 512
        const int k = i & 511;
        wT[i] = f2bf(w[(size_t)k * F_OUT + n]);
    }
}

// ---------------------------------------------------------------------------
// MFMA GEMM: support[50000][96] = x[50000][512] @ w[512][96]
// 256 threads = 4 waves; wave handles 16 rows x 96 cols (6 n-tiles of 16x16).
// A loaded from global f32 -> bf16 in-register; B from wT (L2-resident).
// No LDS, no barriers.
// ---------------------------------------------------------------------------
__global__ __launch_bounds__(256) void gcn_gemm_mfma(const float* __restrict__ x,
                                                     const unsigned short* __restrict__ wT,
                                                     float* __restrict__ support) {
    const int tid  = threadIdx.x;
    const int lane = tid & 63;
    const int wave = tid >> 6;                       // 0..3
    const int r0   = blockIdx.x * 64 + wave * 16;    // wave's row base
    const int lr   = lane & 15;                      // A-row / B-col / C-col
    const int kg   = lane >> 4;                      // k-group 0..3

    f32x4 acc[6];
    #pragma unroll
    for (int t = 0; t < 6; ++t) acc[t] = (f32x4){0.f, 0.f, 0.f, 0.f};

    const int  arow  = r0 + lr;
    const bool rowok = arow < N_NODES;
    const float* aptr = x + (size_t)arow * F_IN + kg * 8;

    for (int k0 = 0; k0 < F_IN; k0 += 32) {
        // ---- A fragment: 8 contiguous f32 -> 8 bf16 ----
        bf16x8 afrag = (bf16x8){0,0,0,0,0,0,0,0};
        if (rowok) {
            const float4 a0 = *reinterpret_cast<const float4*>(aptr + k0);
            const float4 a1 = *reinterpret_cast<const float4*>(aptr + k0 + 4);
            afrag[0] = (short)f2bf(a0.x);
            afrag[1] = (short)f2bf(a0.y);
            afrag[2] = (short)f2bf(a0.z);
            afrag[3] = (short)f2bf(a0.w);
            afrag[4] = (short)f2bf(a1.x);
            afrag[5] = (short)f2bf(a1.y);
            afrag[6] = (short)f2bf(a1.z);
            afrag[7] = (short)f2bf(a1.w);
        }
        // ---- B fragments + MFMA ----
        #pragma unroll
        for (int t = 0; t < 6; ++t) {
            const bf16x8 bfrag = *reinterpret_cast<const bf16x8*>(
                wT + (size_t)(t * 16 + lr) * F_IN + k0 + kg * 8);
            acc[t] = __builtin_amdgcn_mfma_f32_16x16x32_bf16(afrag, bfrag, acc[t], 0, 0, 0);
        }
    }

    // ---- store: C col = lane&15, row = kg*4 + reg ----
    #pragma unroll
    for (int t = 0; t < 6; ++t) {
        #pragma unroll
        for (int r = 0; r < 4; ++r) {
            const int row = r0 + kg * 4 + r;
            if (row < N_NODES)
                support[(size_t)row * F_OUT + t * 16 + lr] = acc[t][r];
        }
    }
}

// ---------------------------------------------------------------------------
// CSR build: histogram -> exclusive scan -> bucket fill
// ---------------------------------------------------------------------------
__global__ __launch_bounds__(256) void k_hist(const int* __restrict__ erow,
                                              int* __restrict__ counts) {
    const int e = blockIdx.x * 256 + threadIdx.x;
    if (e < N_EDGES) atomicAdd(&counts[erow[e]], 1);
}

__global__ __launch_bounds__(256) void k_scan_block(const int* __restrict__ counts,
                                                    int* __restrict__ offsets,
                                                    int* __restrict__ partials) {
    __shared__ int s[256];
    const int t = threadIdx.x;
    const int i = blockIdx.x * 256 + t;
    const int v = (i < N_NODES) ? counts[i] : 0;
    s[t] = v;
    __syncthreads();
    #pragma unroll
    for (int off = 1; off < 256; off <<= 1) {
        const int a = (t >= off) ? s[t - off] : 0;
        __syncthreads();
        s[t] += a;
        __syncthreads();
    }
    if (i < N_NODES) offsets[i] = s[t] - v;
    if (t == 255) partials[blockIdx.x] = s[255];
}

__global__ __launch_bounds__(256) void k_scan_partials(int* __restrict__ partials) {
    __shared__ int s[256];
    const int t = threadIdx.x;
    const int v = (t < SCAN_BLOCKS) ? partials[t] : 0;
    s[t] = v;
    __syncthreads();
    #pragma unroll
    for (int off = 1; off < 256; off <<= 1) {
        const int a = (t >= off) ? s[t - off] : 0;
        __syncthreads();
        s[t] += a;
        __syncthreads();
    }
    if (t < SCAN_BLOCKS) partials[t] = s[t] - v;
}

__global__ __launch_bounds__(256) void k_scan_add(int* __restrict__ offsets,
                                                  const int* __restrict__ partials) {
    const int i = blockIdx.x * 256 + threadIdx.x;
    if (i < N_NODES) offsets[i] += partials[blockIdx.x];
    if (i == 0) offsets[N_NODES] = N_EDGES;
}

__global__ __launch_bounds__(256) void k_fill(const int* __restrict__ erow,
                                              const int* __restrict__ ecol,
                                              const float* __restrict__ eval,
                                              const int* __restrict__ offsets,
                                              int* __restrict__ cursor,
                                              float2* __restrict__ bucket) {
    const int e = blockIdx.x * 256 + threadIdx.x;
    if (e < N_EDGES) {
        const int r = erow[e];
        const int pos = offsets[r] + atomicAdd(&cursor[r], 1);
        bucket[pos] = make_float2(__int_as_float(ecol[e]), eval[e]);
    }
}

// ---------------------------------------------------------------------------
// Gather: thread = (row, f4), f4 in [0,24). No atomics; fused ReLU.
// ---------------------------------------------------------------------------
__global__ __launch_bounds__(256) void k_gather(const int* __restrict__ offsets,
                                                const float2* __restrict__ bucket,
                                                const float* __restrict__ support,
                                                float* __restrict__ out) {
    const int gid = blockIdx.x * 256 + threadIdx.x;
    if (gid >= N_NODES * 24) return;
    const int r  = gid / 24;
    const int f4 = gid - r * 24;

    const int beg = offsets[r];
    const int end = offsets[r + 1];

    float4 acc = make_float4(0.f, 0.f, 0.f, 0.f);
    for (int i = beg; i < end; ++i) {
        const float2 cv = bucket[i];
        const int   c = __float_as_int(cv.x);
        const float v = cv.y;
        const float4 s = *reinterpret_cast<const float4*>(
            support + (size_t)c * F_OUT + f4 * 4);
        acc.x = fmaf(v, s.x, acc.x);
        acc.y = fmaf(v, s.y, acc.y);
        acc.z = fmaf(v, s.z, acc.z);
        acc.w = fmaf(v, s.w, acc.w);
    }

    acc.x = fmaxf(acc.x, 0.f);
    acc.y = fmaxf(acc.y, 0.f);
    acc.z = fmaxf(acc.z, 0.f);
    acc.w = fmaxf(acc.w, 0.f);
    *reinterpret_cast<float4*>(out + (size_t)r * F_OUT + f4 * 4) = acc;
}

extern "C" void kernel_launch(void* const* d_in, const int* in_sizes, int n_in,
                              void* d_out, int out_size, void* d_ws, size_t ws_size,
                              hipStream_t stream) {
    const float* x    = (const float*)d_in[0];
    const int*   erow = (const int*)d_in[1];
    const int*   ecol = (const int*)d_in[2];
    const float* eval = (const float*)d_in[3];
    const float* w    = (const float*)d_in[4];
    float*       out  = (float*)d_out;

    // workspace layout
    float*          support  = (float*)d_ws;                   // 4.8M floats
    int*            counts   = (int*)(support + 4800000);      // 50000
    int*            cursor   = counts + N_NODES;               // 50000
    int*            offsets  = cursor + N_NODES;               // 50001 (pad 50064)
    int*            partials = offsets + 50064;                // 256
    float2*         bucket   = (float2*)(partials + 256);      // 800000 float2
    unsigned short* wT       = (unsigned short*)(bucket + N_EDGES);  // 96*512 bf16

    // zero counts + cursor (contiguous) every call
    hipMemsetAsync(counts, 0, 2 * N_NODES * sizeof(int), stream);

    // wT = bf16(w^T)
    k_wcast<<<(F_OUT * F_IN + 255) / 256, 256, 0, stream>>>(w, wT);

    // support = x @ w   (bf16 MFMA)
    gcn_gemm_mfma<<<(N_NODES + 63) / 64, 256, 0, stream>>>(x, wT, support);

    // CSR build
    const int eblocks = (N_EDGES + 255) / 256;
    k_hist<<<eblocks, 256, 0, stream>>>(erow, counts);
    k_scan_block<<<SCAN_BLOCKS, 256, 0, stream>>>(counts, offsets, partials);
    k_scan_partials<<<1, 256, 0, stream>>>(partials);
    k_scan_add<<<SCAN_BLOCKS, 256, 0, stream>>>(offsets, partials);
    k_fill<<<eblocks, 256, 0, stream>>>(erow, ecol, eval, offsets, cursor, bucket);

    // out = relu(A @ support)
    const int gthreads = N_NODES * 24;
    k_gather<<<(gthreads + 255) / 256, 256, 0, stream>>>(offsets, bucket, support, out);
}

// Round 4
// 206.759 us; speedup vs baseline: 5.4179x; 1.0384x over previous
//
#include <hip/hip_runtime.h>

#define N_NODES 50000
#define F_IN    512
#define F_OUT   96
#define N_EDGES 800000
#define SCAN_BLOCKS ((N_NODES + 255) / 256)   // 196

typedef __attribute__((ext_vector_type(8))) short bf16x8;
typedef __attribute__((ext_vector_type(4))) float f32x4;

typedef const __attribute__((address_space(1))) void* gas_ptr;
typedef __attribute__((address_space(3))) void* las_ptr;

__device__ __forceinline__ void gload_lds16(const float* g, float* l) {
    __builtin_amdgcn_global_load_lds((gas_ptr)g, (las_ptr)l, 16, 0, 0);
}

// f32 -> bf16 round-to-nearest-even (bit pattern)
__device__ __forceinline__ unsigned short f2bf(float f) {
    unsigned int u = __float_as_uint(f);
    unsigned int r = (u + 0x7FFFu + ((u >> 16) & 1u)) >> 16;
    return (unsigned short)r;
}

// ---------------------------------------------------------------------------
// Cast + transpose weight: w[512][96] f32  ->  wT[96][512] bf16
// ---------------------------------------------------------------------------
__global__ __launch_bounds__(256) void k_wcast(const float* __restrict__ w,
                                               unsigned short* __restrict__ wT) {
    const int i = blockIdx.x * 256 + threadIdx.x;
    if (i < F_OUT * F_IN) {
        const int n = i >> 9;
        const int k = i & 511;
        wT[i] = f2bf(w[(size_t)k * F_OUT + n]);
    }
}

// ---------------------------------------------------------------------------
// MFMA GEMM: support[50000][96] = x[50000][512] @ w[512][96]
// BM=64, BK=64, 256 threads = 4 waves (wave w: rows w*16..w*16+15).
// X panel staged f32 in LDS via global_load_lds (coalesced, double-buffered,
// stage-next issued before compute). 16B-granular XOR swizzle on both sides.
// ---------------------------------------------------------------------------
__global__ __launch_bounds__(256) void gcn_gemm_mfma(const float* __restrict__ x,
                                                     const unsigned short* __restrict__ wT,
                                                     float* __restrict__ support) {
    __shared__ float lds[2][64 * 64];   // 2 x 16 KB

    const int tid  = threadIdx.x;
    const int lane = tid & 63;
    const int wave = tid >> 6;
    const int r0   = blockIdx.x * 64;
    const int lr   = lane & 15;        // A-row (within wave tile) / B-col / C-col
    const int kg   = lane >> 4;        // k-group 0..3

    f32x4 acc[6];
    #pragma unroll
    for (int t = 0; t < 6; ++t) acc[t] = (f32x4){0.f, 0.f, 0.f, 0.f};

    // ---- staging: 64 rows x 64 f32 = 1024 x 16B chunks; 4 per thread ----
    auto STAGE = [&](int buf, int p) {
        #pragma unroll
        for (int i = 0; i < 4; ++i) {
            const int chunk = i * 256 + tid;           // 0..1023
            const int row   = chunk >> 4;              // 0..63
            const int s16   = chunk & 15;              // 16B slot in row
            int gr = r0 + row;
            if (gr > N_NODES - 1) gr = N_NODES - 1;    // clamp (row-local garbage ok)
            const int srcb = (s16 * 16) ^ ((row & 15) << 4);   // inverse swizzle
            gload_lds16(x + (size_t)gr * F_IN + p * 64 + (srcb >> 2),
                        &lds[buf][chunk * 4]);
        }
    };

    auto COMPUTE = [&](int buf, int p) {
        const float* base = &lds[buf][0];
        const int row = wave * 16 + lr;                // 0..63 (row&15 == lr)
        #pragma unroll
        for (int ks = 0; ks < 2; ++ks) {
            const int byte0 = ks * 128 + kg * 32;
            const int b0 = byte0        ^ (lr << 4);
            const int b1 = (byte0 + 16) ^ (lr << 4);
            const float4 a0 = *reinterpret_cast<const float4*>(base + row * 64 + (b0 >> 2));
            const float4 a1 = *reinterpret_cast<const float4*>(base + row * 64 + (b1 >> 2));
            bf16x8 af;
            af[0] = (short)f2bf(a0.x); af[1] = (short)f2bf(a0.y);
            af[2] = (short)f2bf(a0.z); af[3] = (short)f2bf(a0.w);
            af[4] = (short)f2bf(a1.x); af[5] = (short)f2bf(a1.y);
            af[6] = (short)f2bf(a1.z); af[7] = (short)f2bf(a1.w);
            #pragma unroll
            for (int t = 0; t < 6; ++t) {
                const bf16x8 bf = *reinterpret_cast<const bf16x8*>(
                    wT + (size_t)(t * 16 + lr) * F_IN + p * 64 + ks * 32 + kg * 8);
                acc[t] = __builtin_amdgcn_mfma_f32_16x16x32_bf16(af, bf, acc[t], 0, 0, 0);
            }
        }
    };

    STAGE(0, 0);
    __syncthreads();
    for (int t = 0; t < 8; ++t) {
        if (t < 7) STAGE((t + 1) & 1, t + 1);   // issue next-panel loads first
        COMPUTE(t & 1, t);                       // MFMA hides load flight
        __syncthreads();                         // vmcnt(0) drain + barrier
    }

    // ---- store: C col = lr, row = kg*4 + reg ----
    #pragma unroll
    for (int t = 0; t < 6; ++t) {
        #pragma unroll
        for (int r = 0; r < 4; ++r) {
            const int row = r0 + wave * 16 + kg * 4 + r;
            if (row < N_NODES)
                support[(size_t)row * F_OUT + t * 16 + lr] = acc[t][r];
        }
    }
}

// ---------------------------------------------------------------------------
// CSR build: histogram -> exclusive scan -> bucket fill
// ---------------------------------------------------------------------------
__global__ __launch_bounds__(256) void k_hist(const int* __restrict__ erow,
                                              int* __restrict__ counts) {
    const int e = blockIdx.x * 256 + threadIdx.x;
    if (e < N_EDGES) atomicAdd(&counts[erow[e]], 1);
}

__global__ __launch_bounds__(256) void k_scan_block(const int* __restrict__ counts,
                                                    int* __restrict__ offsets,
                                                    int* __restrict__ partials) {
    __shared__ int s[256];
    const int t = threadIdx.x;
    const int i = blockIdx.x * 256 + t;
    const int v = (i < N_NODES) ? counts[i] : 0;
    s[t] = v;
    __syncthreads();
    #pragma unroll
    for (int off = 1; off < 256; off <<= 1) {
        const int a = (t >= off) ? s[t - off] : 0;
        __syncthreads();
        s[t] += a;
        __syncthreads();
    }
    if (i < N_NODES) offsets[i] = s[t] - v;
    if (t == 255) partials[blockIdx.x] = s[255];
}

__global__ __launch_bounds__(256) void k_scan_partials(int* __restrict__ partials) {
    __shared__ int s[256];
    const int t = threadIdx.x;
    const int v = (t < SCAN_BLOCKS) ? partials[t] : 0;
    s[t] = v;
    __syncthreads();
    #pragma unroll
    for (int off = 1; off < 256; off <<= 1) {
        const int a = (t >= off) ? s[t - off] : 0;
        __syncthreads();
        s[t] += a;
        __syncthreads();
    }
    if (t < SCAN_BLOCKS) partials[t] = s[t] - v;
}

__global__ __launch_bounds__(256) void k_scan_add(int* __restrict__ offsets,
                                                  const int* __restrict__ partials) {
    const int i = blockIdx.x * 256 + threadIdx.x;
    if (i < N_NODES) offsets[i] += partials[blockIdx.x];
    if (i == 0) offsets[N_NODES] = N_EDGES;
}

__global__ __launch_bounds__(256) void k_fill(const int* __restrict__ erow,
                                              const int* __restrict__ ecol,
                                              const float* __restrict__ eval,
                                              const int* __restrict__ offsets,
                                              int* __restrict__ cursor,
                                              float2* __restrict__ bucket) {
    const int e = blockIdx.x * 256 + threadIdx.x;
    if (e < N_EDGES) {
        const int r = erow[e];
        const int pos = offsets[r] + atomicAdd(&cursor[r], 1);
        bucket[pos] = make_float2(__int_as_float(ecol[e]), eval[e]);
    }
}

// ---------------------------------------------------------------------------
// Gather: thread = (row, f8), f8 in [0,12) -> 8 features each. Fused ReLU.
// ---------------------------------------------------------------------------
__global__ __launch_bounds__(256) void k_gather(const int* __restrict__ offsets,
                                                const float2* __restrict__ bucket,
                                                const float* __restrict__ support,
                                                float* __restrict__ out) {
    const int gid = blockIdx.x * 256 + threadIdx.x;
    if (gid >= N_NODES * 12) return;
    const int r  = gid / 12;
    const int f8 = gid - r * 12;

    const int beg = offsets[r];
    const int end = offsets[r + 1];

    float4 acc0 = make_float4(0.f, 0.f, 0.f, 0.f);
    float4 acc1 = make_float4(0.f, 0.f, 0.f, 0.f);
    for (int i = beg; i < end; ++i) {
        const float2 cv = bucket[i];
        const int   c = __float_as_int(cv.x);
        const float v = cv.y;
        const float* s = support + (size_t)c * F_OUT + f8 * 8;
        const float4 s0 = *reinterpret_cast<const float4*>(s);
        const float4 s1 = *reinterpret_cast<const float4*>(s + 4);
        acc0.x = fmaf(v, s0.x, acc0.x);
        acc0.y = fmaf(v, s0.y, acc0.y);
        acc0.z = fmaf(v, s0.z, acc0.z);
        acc0.w = fmaf(v, s0.w, acc0.w);
        acc1.x = fmaf(v, s1.x, acc1.x);
        acc1.y = fmaf(v, s1.y, acc1.y);
        acc1.z = fmaf(v, s1.z, acc1.z);
        acc1.w = fmaf(v, s1.w, acc1.w);
    }

    acc0.x = fmaxf(acc0.x, 0.f); acc0.y = fmaxf(acc0.y, 0.f);
    acc0.z = fmaxf(acc0.z, 0.f); acc0.w = fmaxf(acc0.w, 0.f);
    acc1.x = fmaxf(acc1.x, 0.f); acc1.y = fmaxf(acc1.y, 0.f);
    acc1.z = fmaxf(acc1.z, 0.f); acc1.w = fmaxf(acc1.w, 0.f);

    float* o = out + (size_t)r * F_OUT + f8 * 8;
    *reinterpret_cast<float4*>(o)     = acc0;
    *reinterpret_cast<float4*>(o + 4) = acc1;
}

extern "C" void kernel_launch(void* const* d_in, const int* in_sizes, int n_in,
                              void* d_out, int out_size, void* d_ws, size_t ws_size,
                              hipStream_t stream) {
    const float* x    = (const float*)d_in[0];
    const int*   erow = (const int*)d_in[1];
    const int*   ecol = (const int*)d_in[2];
    const float* eval = (const float*)d_in[3];
    const float* w    = (const float*)d_in[4];
    float*       out  = (float*)d_out;

    // workspace layout
    float*          support  = (float*)d_ws;                   // 4.8M floats
    int*            counts   = (int*)(support + 4800000);      // 50000
    int*            cursor   = counts + N_NODES;               // 50000
    int*            offsets  = cursor + N_NODES;               // 50001 (pad 50064)
    int*            partials = offsets + 50064;                // 256
    float2*         bucket   = (float2*)(partials + 256);      // 800000 float2
    unsigned short* wT       = (unsigned short*)(bucket + N_EDGES);  // 96*512 bf16

    hipMemsetAsync(counts, 0, 2 * N_NODES * sizeof(int), stream);

    k_wcast<<<(F_OUT * F_IN + 255) / 256, 256, 0, stream>>>(w, wT);

    gcn_gemm_mfma<<<(N_NODES + 63) / 64, 256, 0, stream>>>(x, wT, support);

    const int eblocks = (N_EDGES + 255) / 256;
    k_hist<<<eblocks, 256, 0, stream>>>(erow, counts);
    k_scan_block<<<SCAN_BLOCKS, 256, 0, stream>>>(counts, offsets, partials);
    k_scan_partials<<<1, 256, 0, stream>>>(partials);
    k_scan_add<<<SCAN_BLOCKS, 256, 0, stream>>>(offsets, partials);
    k_fill<<<eblocks, 256, 0, stream>>>(erow, ecol, eval, offsets, cursor, bucket);

    const int gthreads = N_NODES * 12;
    k_gather<<<(gthreads + 255) / 256, 256, 0, stream>>>(offsets, bucket, support, out);
}

// Round 5
// 166.137 us; speedup vs baseline: 6.7426x; 1.2445x over previous
//
#include <hip/hip_runtime.h>

#define N_NODES 50000
#define F_IN    512
#define F_OUT   96
#define N_EDGES 800000
#define SCAN_BLOCKS ((N_NODES + 255) / 256)   // 196

typedef __attribute__((ext_vector_type(8))) short bf16x8;
typedef __attribute__((ext_vector_type(4))) float f32x4;

typedef const __attribute__((address_space(1))) void* gas_ptr;
typedef __attribute__((address_space(3))) void* las_ptr;

__device__ __forceinline__ void gload_lds16(const void* g, void* l) {
    __builtin_amdgcn_global_load_lds((gas_ptr)g, (las_ptr)l, 16, 0, 0);
}

// f32 -> bf16 round-to-nearest-even (bit pattern)
__device__ __forceinline__ unsigned short f2bf(float f) {
    unsigned int u = __float_as_uint(f);
    unsigned int r = (u + 0x7FFFu + ((u >> 16) & 1u)) >> 16;
    return (unsigned short)r;
}
__device__ __forceinline__ float bf2f(unsigned short h) {
    return __uint_as_float(((unsigned int)h) << 16);
}

// ---------------------------------------------------------------------------
// Weight cast: w[512][96] f32 -> wTp[panel p][n][k'] bf16, panel-major,
// XOR-swizzled within each 64-elem row-panel: slot = k' ^ ((n&7)<<3).
// Each panel is a contiguous 12 KB block -> staging is a linear LDS copy.
// ---------------------------------------------------------------------------
__global__ __launch_bounds__(256) void k_wcast(const float* __restrict__ w,
                                               unsigned short* __restrict__ wTp) {
    const int i = blockIdx.x * 256 + threadIdx.x;   // 0..49151
    if (i < F_OUT * F_IN) {
        const int n  = i >> 9;          // out-feature 0..95
        const int k  = i & 511;         // in-feature
        const int p  = k >> 6;          // panel 0..7
        const int kk = k & 63;
        const int slot = kk ^ ((n & 7) << 3);
        wTp[p * (F_OUT * 64) + n * 64 + slot] = f2bf(w[(size_t)k * F_OUT + n]);
    }
}

// ---------------------------------------------------------------------------
// MFMA GEMM: support[50000][96](bf16) = x[50000][512] @ w[512][96]
// BM=64, BK=64, 256 threads = 4 waves (wave w: rows w*16..w*16+15).
// X f32 panel AND B bf16 panel both staged in LDS via global_load_lds
// (linear dest, pre-swizzled source), double-buffered, stage-next-first.
// ---------------------------------------------------------------------------
__global__ __launch_bounds__(256) void gcn_gemm_mfma(const float* __restrict__ x,
                                                     const unsigned short* __restrict__ wTp,
                                                     unsigned short* __restrict__ support) {
    __shared__ float          sX[2][64 * 64];   // 2 x 16 KB
    __shared__ unsigned short sB[2][64 * 96];   // 2 x 12 KB

    const int tid  = threadIdx.x;
    const int lane = tid & 63;
    const int wave = tid >> 6;
    const int r0   = blockIdx.x * 64;
    const int lr   = lane & 15;        // A-row (in wave tile) / B-col / C-col
    const int kg   = lane >> 4;        // k-group 0..3

    f32x4 acc[6];
    #pragma unroll
    for (int t = 0; t < 6; ++t) acc[t] = (f32x4){0.f, 0.f, 0.f, 0.f};

    auto STAGE = [&](int buf, int p) {
        // X: 64 rows x 256 B = 1024 chunks of 16 B; 4 per thread
        #pragma unroll
        for (int i = 0; i < 4; ++i) {
            const int chunk = i * 256 + tid;
            const int row   = chunk >> 4;
            const int s16   = chunk & 15;
            int gr = r0 + row;
            if (gr > N_NODES - 1) gr = N_NODES - 1;
            const int srcb = (s16 * 16) ^ ((row & 15) << 4);   // inverse swizzle
            gload_lds16(x + (size_t)gr * F_IN + p * 64 + (srcb >> 2),
                        &sX[buf][chunk * 4]);
        }
        // B: one contiguous 12 KB panel = 768 chunks of 16 B; 3 per thread
        #pragma unroll
        for (int i = 0; i < 3; ++i) {
            const int chunk = i * 256 + tid;
            gload_lds16(wTp + (size_t)p * (F_OUT * 64) + chunk * 8,
                        &sB[buf][chunk * 8]);
        }
    };

    auto COMPUTE = [&](int buf) {
        const float* xb = &sX[buf][0];
        const char*  bb = (const char*)&sB[buf][0];
        const int xrow = wave * 16 + lr;               // row&15 == lr
        #pragma unroll
        for (int ks = 0; ks < 2; ++ks) {
            const int byte0 = ks * 128 + kg * 32;
            const int b0 = byte0        ^ (lr << 4);
            const int b1 = (byte0 + 16) ^ (lr << 4);
            const float4 a0 = *reinterpret_cast<const float4*>(xb + xrow * 64 + (b0 >> 2));
            const float4 a1 = *reinterpret_cast<const float4*>(xb + xrow * 64 + (b1 >> 2));
            bf16x8 af;
            af[0] = (short)f2bf(a0.x); af[1] = (short)f2bf(a0.y);
            af[2] = (short)f2bf(a0.z); af[3] = (short)f2bf(a0.w);
            af[4] = (short)f2bf(a1.x); af[5] = (short)f2bf(a1.y);
            af[6] = (short)f2bf(a1.z); af[7] = (short)f2bf(a1.w);
            #pragma unroll
            for (int t = 0; t < 6; ++t) {
                const int n    = t * 16 + lr;
                const int boff = (ks * 64 + kg * 16) ^ ((n & 7) << 4);
                const bf16x8 bfr = *reinterpret_cast<const bf16x8*>(bb + n * 128 + boff);
                acc[t] = __builtin_amdgcn_mfma_f32_16x16x32_bf16(af, bfr, acc[t], 0, 0, 0);
            }
        }
    };

    STAGE(0, 0);
    __syncthreads();
    for (int t = 0; t < 8; ++t) {
        if (t < 7) STAGE((t + 1) & 1, t + 1);   // issue next-panel loads first
        COMPUTE(t & 1);                          // compute hides load flight
        __syncthreads();                         // vmcnt drain + barrier
    }

    // ---- store (bf16): C col = lr, row = kg*4 + reg ----
    #pragma unroll
    for (int t = 0; t < 6; ++t) {
        #pragma unroll
        for (int r = 0; r < 4; ++r) {
            const int row = r0 + wave * 16 + kg * 4 + r;
            if (row < N_NODES)
                support[(size_t)row * F_OUT + t * 16 + lr] = f2bf(acc[t][r]);
        }
    }
}

// ---------------------------------------------------------------------------
// CSR build: histogram -> exclusive scan -> bucket fill
// ---------------------------------------------------------------------------
__global__ __launch_bounds__(256) void k_hist(const int* __restrict__ erow,
                                              int* __restrict__ counts) {
    const int e = blockIdx.x * 256 + threadIdx.x;
    if (e < N_EDGES) atomicAdd(&counts[erow[e]], 1);
}

__global__ __launch_bounds__(256) void k_scan_block(const int* __restrict__ counts,
                                                    int* __restrict__ offsets,
                                                    int* __restrict__ partials) {
    __shared__ int s[256];
    const int t = threadIdx.x;
    const int i = blockIdx.x * 256 + t;
    const int v = (i < N_NODES) ? counts[i] : 0;
    s[t] = v;
    __syncthreads();
    #pragma unroll
    for (int off = 1; off < 256; off <<= 1) {
        const int a = (t >= off) ? s[t - off] : 0;
        __syncthreads();
        s[t] += a;
        __syncthreads();
    }
    if (i < N_NODES) offsets[i] = s[t] - v;
    if (t == 255) partials[blockIdx.x] = s[255];
}

__global__ __launch_bounds__(256) void k_scan_partials(int* __restrict__ partials) {
    __shared__ int s[256];
    const int t = threadIdx.x;
    const int v = (t < SCAN_BLOCKS) ? partials[t] : 0;
    s[t] = v;
    __syncthreads();
    #pragma unroll
    for (int off = 1; off < 256; off <<= 1) {
        const int a = (t >= off) ? s[t - off] : 0;
        __syncthreads();
        s[t] += a;
        __syncthreads();
    }
    if (t < SCAN_BLOCKS) partials[t] = s[t] - v;
}

__global__ __launch_bounds__(256) void k_scan_add(int* __restrict__ offsets,
                                                  const int* __restrict__ partials) {
    const int i = blockIdx.x * 256 + threadIdx.x;
    if (i < N_NODES) offsets[i] += partials[blockIdx.x];
    if (i == 0) offsets[N_NODES] = N_EDGES;
}

__global__ __launch_bounds__(256) void k_fill(const int* __restrict__ erow,
                                              const int* __restrict__ ecol,
                                              const float* __restrict__ eval,
                                              const int* __restrict__ offsets,
                                              int* __restrict__ cursor,
                                              float2* __restrict__ bucket) {
    const int e = blockIdx.x * 256 + threadIdx.x;
    if (e < N_EDGES) {
        const int r = erow[e];
        const int pos = offsets[r] + atomicAdd(&cursor[r], 1);
        bucket[pos] = make_float2(__int_as_float(ecol[e]), eval[e]);
    }
}

// ---------------------------------------------------------------------------
// Gather: thread = (row, f8), f8 in [0,12) -> 8 features. bf16 support.
// ---------------------------------------------------------------------------
__global__ __launch_bounds__(256) void k_gather(const int* __restrict__ offsets,
                                                const float2* __restrict__ bucket,
                                                const unsigned short* __restrict__ support,
                                                float* __restrict__ out) {
    const int gid = blockIdx.x * 256 + threadIdx.x;
    if (gid >= N_NODES * 12) return;
    const int r  = gid / 12;
    const int f8 = gid - r * 12;

    const int beg = offsets[r];
    const int end = offsets[r + 1];

    float acc[8];
    #pragma unroll
    for (int j = 0; j < 8; ++j) acc[j] = 0.f;

    for (int i = beg; i < end; ++i) {
        const float2 cv = bucket[i];
        const int   c = __float_as_int(cv.x);
        const float v = cv.y;
        const bf16x8 s8 = *reinterpret_cast<const bf16x8*>(
            support + (size_t)c * F_OUT + f8 * 8);
        #pragma unroll
        for (int j = 0; j < 8; ++j)
            acc[j] = fmaf(v, bf2f((unsigned short)s8[j]), acc[j]);
    }

    float4 o0, o1;
    o0.x = fmaxf(acc[0], 0.f); o0.y = fmaxf(acc[1], 0.f);
    o0.z = fmaxf(acc[2], 0.f); o0.w = fmaxf(acc[3], 0.f);
    o1.x = fmaxf(acc[4], 0.f); o1.y = fmaxf(acc[5], 0.f);
    o1.z = fmaxf(acc[6], 0.f); o1.w = fmaxf(acc[7], 0.f);

    float* o = out + (size_t)r * F_OUT + f8 * 8;
    *reinterpret_cast<float4*>(o)     = o0;
    *reinterpret_cast<float4*>(o + 4) = o1;
}

extern "C" void kernel_launch(void* const* d_in, const int* in_sizes, int n_in,
                              void* d_out, int out_size, void* d_ws, size_t ws_size,
                              hipStream_t stream) {
    const float* x    = (const float*)d_in[0];
    const int*   erow = (const int*)d_in[1];
    const int*   ecol = (const int*)d_in[2];
    const float* eval = (const float*)d_in[3];
    const float* w    = (const float*)d_in[4];
    float*       out  = (float*)d_out;

    // workspace layout (support slot kept float-sized; bf16 uses half of it)
    unsigned short* support  = (unsigned short*)d_ws;          // 4.8M bf16
    int*            counts   = (int*)((float*)d_ws + 4800000); // 50000
    int*            cursor   = counts + N_NODES;               // 50000
    int*            offsets  = cursor + N_NODES;               // 50001 (pad 50064)
    int*            partials = offsets + 50064;                // 256
    float2*         bucket   = (float2*)(partials + 256);      // 800000 float2
    unsigned short* wTp      = (unsigned short*)(bucket + N_EDGES);  // 96*512 bf16

    hipMemsetAsync(counts, 0, 2 * N_NODES * sizeof(int), stream);

    k_wcast<<<(F_OUT * F_IN + 255) / 256, 256, 0, stream>>>(w, wTp);

    gcn_gemm_mfma<<<(N_NODES + 63) / 64, 256, 0, stream>>>(x, wTp, support);

    const int eblocks = (N_EDGES + 255) / 256;
    k_hist<<<eblocks, 256, 0, stream>>>(erow, counts);
    k_scan_block<<<SCAN_BLOCKS, 256, 0, stream>>>(counts, offsets, partials);
    k_scan_partials<<<1, 256, 0, stream>>>(partials);
    k_scan_add<<<SCAN_BLOCKS, 256, 0, stream>>>(offsets, partials);
    k_fill<<<eblocks, 256, 0, stream>>>(erow, ecol, eval, offsets, cursor, bucket);

    const int gthreads = N_NODES * 12;
    k_gather<<<(gthreads + 255) / 256, 256, 0, stream>>>(offsets, bucket, support, out);
}